// Round 14
// baseline (1287.065 us; speedup 1.0000x reference)
//
#include <hip/hip_runtime.h>
#include <stdint.h>

typedef unsigned long long u64;
typedef unsigned int u32;
typedef unsigned short u16;
typedef u32 u32x4 __attribute__((ext_vector_type(4)));
typedef float f32x4 __attribute__((ext_vector_type(4)));

// Fixed problem shape (N=100000, E=1600000, C_IN=C_OUT=128, NHEADS=4)
#define CIN 128
#define NN 100000
#define EE 1600000
#define N4 (NN * 4)
#define EK_OFF (NN * CIN)          // 12,800,000 f32
#define NM_OFF (EK_OFF + EE)       // 14,400,000
#define SL_OFF (NM_OFF + NN)       // 14,500,000
#define GRID 2048                  // 8 blocks/CU x 256 CUs -> co-resident (64 VGPR cap, 4KB LDS)
#define BLK 256

__device__ __forceinline__ float bf2f(u16 v) {
    union { u32 u; float f; } cv;
    cv.u = ((u32)v) << 16;
    return cv.f;
}

__device__ __forceinline__ u16 f2bf(float f) {      // RNE f32 -> bf16
    u32 b = __float_as_uint(f);
    return (u16)((b + 0x7FFFu + ((b >> 16) & 1u)) >> 16);
}

// Monotonic map: f32 -> u32 preserving total order. Never 0 for finite input,
// so key==0 means "empty slot".
__device__ __forceinline__ u32 mono32(float f) {
    u32 u = __float_as_uint(f);
    return ((int)u >= 0) ? (u | 0x80000000u) : ~u;
}

// Soft grid barrier, stale-proof version. r13 post-mortem: a RELAXED agent
// *load* poll reads the remote XCD's stale L2 line until eviction (~120 us
// per barrier). RMWs always execute at the memory-side coherence point
// (proven by the 32 B/atomic WRITE signature, r4-r10), so polling with
// fetch_add(0, ACQUIRE) can never see a stale value. All threads then run
// __threadfence() to invalidate vector L1 (phase N cached lines that phase
// N+1 re-reads). Co-residency: GRID = 8 blocks/CU by __launch_bounds__.
__device__ __forceinline__ void grid_barrier(u32* bar, u32 target) {
    __syncthreads();
    if (threadIdx.x == 0) {
        __hip_atomic_fetch_add(bar, 1u, __ATOMIC_ACQ_REL, __HIP_MEMORY_SCOPE_AGENT);
        int spins = 0;
        while (__hip_atomic_fetch_add(bar, 0u, __ATOMIC_ACQUIRE, __HIP_MEMORY_SCOPE_AGENT) < target) {
            __builtin_amdgcn_s_sleep(16);
            if (++spins > (1 << 20)) break;   // failsafe: clean numeric fail, no hang
        }
    }
    __syncthreads();
    __threadfence();   // all threads: invalidate L1 so post-barrier reads are fresh
}

// ---------------------------------------------------------------------------
// One kernel, 4 phases, 3 soft barriers. Zero fills via hipMemsetAsync.
//  P1: V table (LDS) + s-tables (bf16x4)          [r11 k_s core]
//  P2: fused segmax+argmin, test-then-atomic       [r11 k_edge]
//  P3: decode winners -> node_mask                 [r11 k_select]
//  P4: edge_keep + node_mask f32 + slices          [r11 k_final]
__global__ __launch_bounds__(256, 8) void k_fused(const u16* __restrict__ x,
                                                  const int* __restrict__ ei,
                                                  const int* __restrict__ sl,
                                                  const u16* __restrict__ W,
                                                  const u16* __restrict__ att,
                                                  float* __restrict__ out,
                                                  ushort4* __restrict__ sjb,
                                                  ushort4* __restrict__ sib,
                                                  int* __restrict__ nm,
                                                  u64* __restrict__ seg,
                                                  u32* __restrict__ bar) {
    const int stride = GRID * BLK;
    const int tid = blockIdx.x * BLK + threadIdx.x;

    // ---------------- phase 1: V table + s-tables ----------------
    __shared__ float Vl[1024];
    for (int slot = threadIdx.x; slot < 1024; slot += BLK) {
        int k = slot >> 3, h8 = slot & 7;
        int head = h8 & 3;
        int off = (h8 < 4) ? 0 : 32;
        float acc = 0.0f;
        #pragma unroll
        for (int c = 0; c < 32; ++c)
            acc += bf2f(W[k * CIN + head * 32 + c]) * bf2f(att[head * 64 + off + c]);
        Vl[slot] = acc;
    }
    __syncthreads();
    for (int n = tid; n < NN; n += stride) {
        const uint4* row = (const uint4*)(x + (size_t)n * CIN);
        float acc[8];
        #pragma unroll
        for (int h = 0; h < 8; ++h) acc[h] = 0.0f;
        #pragma unroll 4
        for (int q = 0; q < 16; ++q) {
            uint4 v = row[q];
            u32 w[4] = { v.x, v.y, v.z, v.w };
            #pragma unroll
            for (int j = 0; j < 4; ++j) {
                float x0 = bf2f((u16)(w[j] & 0xFFFFu));
                float x1 = bf2f((u16)(w[j] >> 16));
                int k0 = q * 8 + j * 2;
                #pragma unroll
                for (int h = 0; h < 8; ++h) acc[h] += x0 * Vl[k0 * 8 + h];
                #pragma unroll
                for (int h = 0; h < 8; ++h) acc[h] += x1 * Vl[(k0 + 1) * 8 + h];
            }
        }
        ushort4 a, b;
        a.x = f2bf(acc[0]); a.y = f2bf(acc[1]); a.z = f2bf(acc[2]); a.w = f2bf(acc[3]);
        b.x = f2bf(acc[4]); b.y = f2bf(acc[5]); b.z = f2bf(acc[6]); b.w = f2bf(acc[7]);
        sjb[n] = a;
        sib[n] = b;
    }

    grid_barrier(bar, 1 * GRID);

    // ---------------- phase 2: fused argmax (test-then-atomic) ----------------
    // key=(mono32(alpha)<<32)|~e: max score, tie -> min edge id. Stale test
    // reads are only ever smaller -> extra atomic at worst (seg monotone).
    for (int e = tid; e < EE; e += stride) {
        int src = ei[e], dst = ei[EE + e];
        ushort4 sj = sjb[src];
        ushort4 si = sib[dst];
        u64 lo = (u64)(u32)(~(u32)e);
        u64* slot = seg + (size_t)src * 4;
        ulonglong2 c01 = *(const ulonglong2*)(slot);
        ulonglong2 c23 = *(const ulonglong2*)(slot + 2);
        u64 k0 = ((u64)mono32(bf2f(sj.x) + bf2f(si.x)) << 32) | lo;
        u64 k1 = ((u64)mono32(bf2f(sj.y) + bf2f(si.y)) << 32) | lo;
        u64 k2 = ((u64)mono32(bf2f(sj.z) + bf2f(si.z)) << 32) | lo;
        u64 k3 = ((u64)mono32(bf2f(sj.w) + bf2f(si.w)) << 32) | lo;
        if (k0 > c01.x) atomicMax(&slot[0], k0);
        if (k1 > c01.y) atomicMax(&slot[1], k1);
        if (k2 > c23.x) atomicMax(&slot[2], k2);
        if (k3 > c23.y) atomicMax(&slot[3], k3);
    }

    grid_barrier(bar, 2 * GRID);

    // ---------------- phase 3: decode winners -> node_mask ----------------
    for (int t = tid; t < N4; t += stride) {
        u64 m = seg[t];
        if (m) {
            int e = (int)(~(u32)m);
            nm[ei[EE + e]] = 1;     // race-benign: all writers store 1
        }
    }

    grid_barrier(bar, 3 * GRID);

    // ---------------- phase 4: epilogue ----------------
    for (int t = tid; t < EE / 4; t += stride) {
        int4 srcs = ((const int4*)ei)[t];
        int4 dsts = ((const int4*)(ei + EE))[t];
        f32x4 v;
        v.x = (nm[srcs.x] & nm[dsts.x]) ? 1.0f : 0.0f;
        v.y = (nm[srcs.y] & nm[dsts.y]) ? 1.0f : 0.0f;
        v.z = (nm[srcs.z] & nm[dsts.z]) ? 1.0f : 0.0f;
        v.w = (nm[srcs.w] & nm[dsts.w]) ? 1.0f : 0.0f;
        __builtin_nontemporal_store(v, &((f32x4*)(out + EK_OFF))[t]);
    }
    for (int t = tid; t < NN; t += stride) out[NM_OFF + t] = nm[t] ? 1.0f : 0.0f;
    if (tid < 2) out[SL_OFF + tid] = (float)sl[tid];   // 0 and 100000, exact
}

// ---------------------------------------------------------------------------
extern "C" void kernel_launch(void* const* d_in, const int* in_sizes, int n_in,
                              void* d_out, int out_size, void* d_ws, size_t ws_size,
                              hipStream_t stream) {
    // Bind inputs by UNIQUE flat size (permutation-proof):
    const u16* x = nullptr; const int* ei = nullptr; const int* sl = nullptr;
    const u16* W = nullptr; const u16* att = nullptr;
    for (int i = 0; i < n_in; ++i) {
        switch (in_sizes[i]) {
            case NN * CIN:   x   = (const u16*)d_in[i]; break;
            case 2 * EE:     ei  = (const int*)d_in[i]; break;
            case 2:          sl  = (const int*)d_in[i]; break;
            case CIN * CIN:  W   = (const u16*)d_in[i]; break;
            case 256:        att = (const u16*)d_in[i]; break;
            default: break;
        }
    }
    if (!x || !ei || !sl || !W || !att) return;

    float* out = (float*)d_out;             // f32 concat, return order

    // workspace: [bar 64B | seg N4*8 (3.2MB) | nm N*4 (0.4MB) | sjb N*8 | sib N*8]
    char* ws = (char*)d_ws;
    u32*     bar = (u32*)    (ws);
    u64*     seg = (u64*)    (ws + 64);
    int*     nm  = (int*)    (ws + 64 + (size_t)N4 * 8);
    ushort4* sjb = (ushort4*)(ws + 64 + (size_t)N4 * 8 + (size_t)NN * 4);
    ushort4* sib = (ushort4*)(ws + 64 + (size_t)N4 * 8 + (size_t)NN * 4 + (size_t)NN * 8);

    // Zero-fills via async memset (graph-capturable):
    hipMemsetAsync(ws, 0, 64 + (size_t)N4 * 8 + (size_t)NN * 4, stream);  // bar+seg+nm
    hipMemsetAsync(out, 0, (size_t)EK_OFF * 4, stream);                   // x_out region

    k_fused<<<GRID, BLK, 0, stream>>>(x, ei, sl, W, att, out, sjb, sib, nm, seg, bar);
}

// Round 15
// 211.397 us; speedup vs baseline: 6.0884x; 6.0884x over previous
//
#include <hip/hip_runtime.h>
#include <stdint.h>

typedef unsigned long long u64;
typedef unsigned int u32;
typedef unsigned short u16;
typedef int i32x4 __attribute__((ext_vector_type(4)));
typedef float f32x4 __attribute__((ext_vector_type(4)));

// Fixed problem shape (N=100000, E=1600000, C_IN=C_OUT=128, NHEADS=4)
#define CIN 128
#define NN 100000
#define EE 1600000
#define N4 (NN * 4)

__device__ __forceinline__ float bf2f(u16 v) {
    union { u32 u; float f; } cv;
    cv.u = ((u32)v) << 16;
    return cv.f;
}

__device__ __forceinline__ u16 f2bf(float f) {      // RNE f32 -> bf16
    u32 b = __float_as_uint(f);
    return (u16)((b + 0x7FFFu + ((b >> 16) & 1u)) >> 16);
}

// Monotonic map: f32 -> u32 preserving total order. Never 0 for finite input,
// so key==0 means "empty slot".
__device__ __forceinline__ u32 mono32(float f) {
    u32 u = __float_as_uint(f);
    return ((int)u >= 0) ? (u | 0x80000000u) : ~u;
}

// ---------------------------------------------------------------------------
// k_s: pure V-table (LDS) + s-table GEMV (zero-fills offloaded to memset).
// __launch_bounds__(256,4) caps VGPR at 128 (r10: 256 VGPR -> latency-bound);
// unroll 4 keeps <=4 uint4 in flight.
__global__ __launch_bounds__(256, 4) void k_s(const u16* __restrict__ x,
                                              const u16* __restrict__ W,
                                              const u16* __restrict__ att,
                                              ushort4* __restrict__ sjb,
                                              ushort4* __restrict__ sib) {
    __shared__ float Vl[1024];
    for (int slot = threadIdx.x; slot < 1024; slot += 256) {
        int k = slot >> 3, h8 = slot & 7;
        int head = h8 & 3;
        int off = (h8 < 4) ? 0 : 32;
        float acc = 0.0f;
        #pragma unroll
        for (int c = 0; c < 32; ++c)
            acc += bf2f(W[k * CIN + head * 32 + c]) * bf2f(att[head * 64 + off + c]);
        Vl[slot] = acc;
    }
    __syncthreads();

    int stride = gridDim.x * blockDim.x;
    for (int n = blockIdx.x * blockDim.x + threadIdx.x; n < NN; n += stride) {
        const uint4* row = (const uint4*)(x + (size_t)n * CIN);
        float acc[8];
        #pragma unroll
        for (int h = 0; h < 8; ++h) acc[h] = 0.0f;
        #pragma unroll 4
        for (int q = 0; q < 16; ++q) {
            uint4 v = row[q];
            u32 w[4] = { v.x, v.y, v.z, v.w };
            #pragma unroll
            for (int j = 0; j < 4; ++j) {
                float x0 = bf2f((u16)(w[j] & 0xFFFFu));
                float x1 = bf2f((u16)(w[j] >> 16));
                int k0 = q * 8 + j * 2;
                #pragma unroll
                for (int h = 0; h < 8; ++h) acc[h] += x0 * Vl[k0 * 8 + h];
                #pragma unroll
                for (int h = 0; h < 8; ++h) acc[h] += x1 * Vl[(k0 + 1) * 8 + h];
            }
        }
        ushort4 a, b;
        a.x = f2bf(acc[0]); a.y = f2bf(acc[1]); a.z = f2bf(acc[2]); a.w = f2bf(acc[3]);
        b.x = f2bf(acc[4]); b.y = f2bf(acc[5]); b.z = f2bf(acc[6]); b.w = f2bf(acc[7]);
        sjb[n] = a;
        sib[n] = b;
    }
}

// ---------------------------------------------------------------------------
// Single-pass fused argmax on ONE shared table. key=(mono32(alpha)<<32)|~e:
// max score, tie -> min edge id. Test-then-atomic with full degree (~16)
// visible -> ~H(16)=3.4 atomics/slot (~1.35M; r10 WRITE 24 MB confirms).
// ei columns are read once -> nontemporal, so the 12.8 MB stream doesn't
// evict the seg (3.2 MB) + s (1.6 MB) working set from per-XCD L2.
__global__ __launch_bounds__(256) void k_edge(const int* __restrict__ ei,
                                              const ushort4* __restrict__ sjb,
                                              const ushort4* __restrict__ sib,
                                              u64* __restrict__ seg, int n_edges) {
    int e = blockIdx.x * blockDim.x + threadIdx.x;
    if (e >= n_edges) return;
    int src = __builtin_nontemporal_load(ei + e);
    int dst = __builtin_nontemporal_load(ei + n_edges + e);
    ushort4 sj = sjb[src];
    ushort4 si = sib[dst];
    u64 lo = (u64)(u32)(~(u32)e);
    u64* slot = seg + (size_t)src * 4;
    ulonglong2 c01 = *(const ulonglong2*)(slot);
    ulonglong2 c23 = *(const ulonglong2*)(slot + 2);
    u64 k0 = ((u64)mono32(bf2f(sj.x) + bf2f(si.x)) << 32) | lo;
    u64 k1 = ((u64)mono32(bf2f(sj.y) + bf2f(si.y)) << 32) | lo;
    u64 k2 = ((u64)mono32(bf2f(sj.z) + bf2f(si.z)) << 32) | lo;
    u64 k3 = ((u64)mono32(bf2f(sj.w) + bf2f(si.w)) << 32) | lo;
    if (k0 > c01.x) atomicMax(&slot[0], k0);
    if (k1 > c01.y) atomicMax(&slot[1], k1);
    if (k2 > c23.x) atomicMax(&slot[2], k2);
    if (k3 > c23.y) atomicMax(&slot[3], k3);
}

// ---------------------------------------------------------------------------
// Decode winning edge per (src,head); set node_mask[dst].
__global__ void k_select(const int* __restrict__ ei, const u64* __restrict__ seg,
                         int* __restrict__ nm, int n4, int n_edges) {
    int t = blockIdx.x * blockDim.x + threadIdx.x;
    if (t >= n4) return;
    u64 m = __builtin_nontemporal_load(seg + t);
    if (m) {
        int e = (int)(~(u32)m);
        nm[ei[n_edges + e]] = 1;     // race-benign: all writers store 1
    }
}

// ---------------------------------------------------------------------------
// Fused epilogue: edge_keep (4 edges/thread, nt f32x4 stores, nt i32x4 ei
// loads) + node_mask f32 + batch_slices f32.
__global__ void k_final(const int* __restrict__ ei, const int* __restrict__ nm,
                        const int* __restrict__ slices, float* __restrict__ out,
                        int n_edges, int n_nodes, int ek_off, int nm_off, int sl_off) {
    int t = blockIdx.x * blockDim.x + threadIdx.x;
    int e0 = 4 * t;
    if (e0 < n_edges) {
        i32x4 srcs = __builtin_nontemporal_load(&((const i32x4*)ei)[t]);
        i32x4 dsts = __builtin_nontemporal_load(&((const i32x4*)(ei + n_edges))[t]);
        f32x4 v;
        v.x = (nm[srcs.x] & nm[dsts.x]) ? 1.0f : 0.0f;
        v.y = (nm[srcs.y] & nm[dsts.y]) ? 1.0f : 0.0f;
        v.z = (nm[srcs.z] & nm[dsts.z]) ? 1.0f : 0.0f;
        v.w = (nm[srcs.w] & nm[dsts.w]) ? 1.0f : 0.0f;
        __builtin_nontemporal_store(v, &((f32x4*)(out + ek_off))[t]);
    }
    if (t < n_nodes) out[nm_off + t] = nm[t] ? 1.0f : 0.0f;
    if (t < 2) out[sl_off + t] = (float)slices[t];   // 0 and 100000, exact
}

// ---------------------------------------------------------------------------
extern "C" void kernel_launch(void* const* d_in, const int* in_sizes, int n_in,
                              void* d_out, int out_size, void* d_ws, size_t ws_size,
                              hipStream_t stream) {
    // Bind inputs by UNIQUE flat size (permutation-proof):
    const u16* x = nullptr; const int* ei = nullptr; const int* sl = nullptr;
    const u16* W = nullptr; const u16* att = nullptr;
    for (int i = 0; i < n_in; ++i) {
        switch (in_sizes[i]) {
            case NN * CIN:   x   = (const u16*)d_in[i]; break;
            case 2 * EE:     ei  = (const int*)d_in[i]; break;
            case 2:          sl  = (const int*)d_in[i]; break;
            case CIN * CIN:  W   = (const u16*)d_in[i]; break;
            case 256:        att = (const u16*)d_in[i]; break;
            default: break;
        }
    }
    if (!x || !ei || !sl || !W || !att) return;

    float* out = (float*)d_out;             // f32 concat, return order
    const int N = NN;
    const int E = EE;

    // output layout (f32): [x_out N*128][edge_keep E][node_mask N][slices 2]
    const int ek_off = N * CIN;
    const int nm_off = ek_off + E;
    const int sl_off = nm_off + N;

    // workspace: [seg N4*8 (3.2MB) | nm N*4 (0.4MB) | sjb N*8 | sib N*8]
    // seg+nm is one contiguous memset-zero region.
    char* ws = (char*)d_ws;
    u64*     seg = (u64*)    (ws);
    int*     nm  = (int*)    (ws + (size_t)N4 * 8);
    ushort4* sjb = (ushort4*)(ws + (size_t)N4 * 8 + (size_t)N * 4);
    ushort4* sib = (ushort4*)(ws + (size_t)N4 * 8 + (size_t)N * 4 + (size_t)N * 8);

    // Zero-fills via async memset (graph-capturable DMA, ~10 us total):
    hipMemsetAsync(ws, 0, (size_t)N4 * 8 + (size_t)N * 4, stream);   // seg+nm
    hipMemsetAsync(out, 0, (size_t)ek_off * 4, stream);              // x_out region

    k_s<<<1024, 256, 0, stream>>>(x, W, att, sjb, sib);
    k_edge<<<(E + 255) / 256, 256, 0, stream>>>(ei, sjb, sib, seg, E);
    k_select<<<(N4 + 255) / 256, 256, 0, stream>>>(ei, seg, nm, N4, E);
    k_final<<<(E / 4 + 255) / 256, 256, 0, stream>>>(ei, nm, sl, out, E, N, ek_off, nm_off, sl_off);
}